// Round 1
// baseline (39.127 us; speedup 1.0000x reference)
//
#include <hip/hip_runtime.h>

#define IMG_H 512
#define IMG_W 512
#define MAX_STREAKS 64

// Kernel 1: rasterize overlap count K[h][w] and store f = (1-a)^K into ws.
__global__ void __launch_bounds__(256)
rain_factor_kernel(const float* __restrict__ alpha,
                   const int* __restrict__ xc,
                   const int* __restrict__ y0,
                   const int* __restrict__ y1_off,
                   float* __restrict__ f,
                   int n_streaks) {
    __shared__ int s_xc[MAX_STREAKS], s_y0[MAX_STREAKS], s_y1[MAX_STREAKS];
    int tid = threadIdx.x;
    if (tid < n_streaks) {
        s_xc[tid] = xc[tid];
        s_y0[tid] = y0[tid];
        s_y1[tid] = y1_off[tid] + IMG_H / 2;
    }
    __syncthreads();

    float l2f = __log2f(1.0f - alpha[0]);

    int idx = blockIdx.x * blockDim.x + threadIdx.x;
    if (idx >= IMG_H * IMG_W) return;
    int h = idx >> 9;        // / IMG_W
    int w = idx & (IMG_W - 1);

    int k = 0;
    #pragma unroll 8
    for (int s = 0; s < n_streaks; ++s) {
        int c  = s_xc[s];
        int c0 = c - 1 > 0 ? c - 1 : 0;
        int hit = (h >= s_y0[s]) & (h < s_y1[s]) & (w >= c0) & (w < c + 1);
        k += hit;
    }
    // (1-a)^k; k==0 -> exp2(0) == 1.0 exactly
    f[idx] = exp2f(l2f * (float)k);
}

// Kernel 2: out = clip(x*f + (1-f), 0, 1), float4-vectorized grid-stride.
__global__ void __launch_bounds__(256)
rain_apply_kernel(const float4* __restrict__ x,
                  const float4* __restrict__ f,
                  float4* __restrict__ out,
                  int n4) {
    const int fmask = (IMG_H * IMG_W / 4) - 1;  // 65535
    int stride = gridDim.x * blockDim.x;
    for (int i = blockIdx.x * blockDim.x + threadIdx.x; i < n4; i += stride) {
        float4 xv = x[i];
        float4 fv = f[i & fmask];
        float4 o;
        o.x = fminf(fmaxf(fmaf(xv.x, fv.x, 1.0f - fv.x), 0.0f), 1.0f);
        o.y = fminf(fmaxf(fmaf(xv.y, fv.y, 1.0f - fv.y), 0.0f), 1.0f);
        o.z = fminf(fmaxf(fmaf(xv.z, fv.z, 1.0f - fv.z), 0.0f), 1.0f);
        o.w = fminf(fmaxf(fmaf(xv.w, fv.w, 1.0f - fv.w), 0.0f), 1.0f);
        out[i] = o;
    }
}

extern "C" void kernel_launch(void* const* d_in, const int* in_sizes, int n_in,
                              void* d_out, int out_size, void* d_ws, size_t ws_size,
                              hipStream_t stream) {
    const float* x      = (const float*)d_in[0];
    const float* alpha  = (const float*)d_in[1];
    const int*   xc     = (const int*)d_in[2];
    const int*   y0     = (const int*)d_in[3];
    const int*   y1_off = (const int*)d_in[4];
    float* out = (float*)d_out;
    float* f   = (float*)d_ws;   // needs IMG_H*IMG_W*4 = 1 MiB

    int n_streaks = in_sizes[2];

    // Kernel 1: 512*512 pixels
    {
        int threads = 256;
        int blocks = (IMG_H * IMG_W + threads - 1) / threads;  // 1024
        rain_factor_kernel<<<blocks, threads, 0, stream>>>(alpha, xc, y0, y1_off, f, n_streaks);
    }

    // Kernel 2: elementwise blend over all B*C*H*W elements
    {
        int n4 = out_size / 4;   // 6,291,456 float4s
        int threads = 256;
        int blocks = 2048;       // grid-stride, ~12 float4 per thread
        rain_apply_kernel<<<blocks, threads, 0, stream>>>(
            (const float4*)x, (const float4*)f, (float4*)out, n4);
    }
}